// Round 1
// baseline (567.833 us; speedup 1.0000x reference)
//
#include <hip/hip_runtime.h>
#include <math.h>

#define H   128
#define NS  1024
#define NE  512
#define M   1024

// tanh(x) = 1 - 2/(exp(2x)+1); exact saturation at both ends.
__device__ __forceinline__ float fast_tanh(float x) {
    float e = __expf(2.0f * x);                 // +inf for large x -> rcp = 0 -> 1
    float r = __builtin_amdgcn_rcpf(1.0f + e);  // ~1 ulp approx rcp
    return 1.0f - 2.0f * r;
}

// out[r,h] = bias[h] + sum_k X[r,k] * W[h, off+k]   (W is [H, 2H] row-major)
__global__ __launch_bounds__(H) void k_proj(const float* __restrict__ X,
                                            const float* __restrict__ W,
                                            const float* __restrict__ bias,
                                            float* __restrict__ out, int off) {
    __shared__ float xr[H];
    int r = blockIdx.x;
    int h = threadIdx.x;
    xr[h] = X[r * H + h];
    __syncthreads();
    const float* wrow = W + h * (2 * H) + off;
    float acc = bias ? bias[h] : 0.0f;
    #pragma unroll 8
    for (int k = 0; k < H; ++k) acc += xr[k] * wrow[k];
    out[r * H + h] = acc;
}

// S[n,m] = sum_h ws[h] * tanh(A[n,h] + B[m,h]);  32x32 tile per block.
__global__ __launch_bounds__(256) void k_score(const float* __restrict__ A,
                                               const float* __restrict__ B,
                                               const float* __restrict__ wsv,
                                               float* __restrict__ S) {
    __shared__ float As[32][H + 1];
    __shared__ float Bs[32][H + 1];
    __shared__ float wls[H];
    int n0 = blockIdx.y * 32;
    int m0 = blockIdx.x * 32;
    int tid = threadIdx.x;
    for (int i = tid; i < 32 * H; i += 256) {
        int rr = i >> 7, cc = i & (H - 1);
        As[rr][cc] = A[(n0 + rr) * H + cc];
        Bs[rr][cc] = B[(m0 + rr) * H + cc];
    }
    if (tid < H) wls[tid] = wsv[tid];
    __syncthreads();

    int tm  = tid & 31;   // m within tile
    int tn4 = tid >> 5;   // 0..7 ; handles n = tn4 + 8*j
    float acc[4] = {0.f, 0.f, 0.f, 0.f};
    #pragma unroll 4
    for (int h = 0; h < H; ++h) {
        float b = Bs[tm][h];
        float w = wls[h];
        #pragma unroll
        for (int j = 0; j < 4; ++j)
            acc[j] += w * fast_tanh(As[tn4 + 8 * j][h] + b);
    }
    #pragma unroll
    for (int j = 0; j < 4; ++j)
        S[(n0 + tn4 + 8 * j) * M + m0 + tm] = acc[j];
}

// Per-column (over n) max and sum(exp(s - max)).  One thread per column.
__global__ __launch_bounds__(256) void k_stats(const float* __restrict__ S, int N,
                                               float* __restrict__ mx,
                                               float* __restrict__ sm) {
    int c = blockIdx.x * blockDim.x + threadIdx.x;
    float m = -1e30f;
    for (int n = 0; n < N; ++n) m = fmaxf(m, S[n * M + c]);
    float s = 0.f;
    for (int n = 0; n < N; ++n) s += __expf(S[n * M + c] - m);
    mx[c] = m;
    sm[c] = s;
}

// ctx[m,h] = (1/Z_m) * sum_n exp(S[n,m]-mx_m) * X[n,h];  8 m's per block,
// 256 threads = 2 groups of 128 (h), each group handles half the n-chunk.
#define TMD 8
__global__ __launch_bounds__(256) void k_ctx(const float* __restrict__ S,
                                             const float* __restrict__ X,
                                             const float* __restrict__ mx,
                                             const float* __restrict__ sm,
                                             float* __restrict__ ctx, int N) {
    __shared__ float w[256][TMD + 1];
    __shared__ float part[H][TMD];
    int m0 = blockIdx.x * TMD;
    int tid = threadIdx.x;
    int h = tid & (H - 1);
    int g = tid >> 7;  // 0 or 1
    float cm[TMD], cz[TMD];
    #pragma unroll
    for (int j = 0; j < TMD; ++j) {
        cm[j] = mx[m0 + j];
        cz[j] = __builtin_amdgcn_rcpf(sm[m0 + j]);
    }
    float acc[TMD];
    #pragma unroll
    for (int j = 0; j < TMD; ++j) acc[j] = 0.f;

    for (int nc = 0; nc < N; nc += 256) {
        #pragma unroll
        for (int j = 0; j < TMD; ++j)
            w[tid][j] = __expf(S[(nc + tid) * M + m0 + j] - cm[j]);
        __syncthreads();
        int base = g * 128;
        #pragma unroll 8
        for (int nn = 0; nn < 128; ++nn) {
            float x = X[(nc + base + nn) * H + h];
            #pragma unroll
            for (int j = 0; j < TMD; ++j) acc[j] += w[base + nn][j] * x;
        }
        __syncthreads();
    }
    if (g == 1) {
        #pragma unroll
        for (int j = 0; j < TMD; ++j) part[h][j] = acc[j];
    }
    __syncthreads();
    if (g == 0) {
        #pragma unroll
        for (int j = 0; j < TMD; ++j)
            ctx[(m0 + j) * H + h] = (acc[j] + part[h][j]) * cz[j];
    }
}

// coherence[m] = b_coh + sum_a W_coh[a] * tanh(b_lin[a] + feats[m] . W_lin[a,:])
__global__ __launch_bounds__(H) void k_final(const float* __restrict__ attender,
                                             const float* __restrict__ ctx_s,
                                             const float* __restrict__ ctx_e,
                                             const float* __restrict__ W_lin,
                                             const float* __restrict__ b_lin,
                                             const float* __restrict__ W_coh,
                                             const float* __restrict__ b_coh,
                                             float* __restrict__ out) {
    __shared__ float f[3 * H];
    __shared__ float red[2];
    int m = blockIdx.x;
    int t = threadIdx.x;
    f[t]         = attender[m * H + t];
    f[H + t]     = ctx_s[m * H + t];
    f[2 * H + t] = ctx_e[m * H + t];
    __syncthreads();
    const float* wr = W_lin + t * (3 * H);
    float acc = b_lin[t];
    #pragma unroll 8
    for (int k = 0; k < 3 * H; ++k) acc += f[k] * wr[k];
    float v = fast_tanh(acc) * W_coh[t];
    #pragma unroll
    for (int off = 32; off > 0; off >>= 1) v += __shfl_down(v, off, 64);
    if ((t & 63) == 0) red[t >> 6] = v;
    __syncthreads();
    if (t == 0) out[m] = red[0] + red[1] + b_coh[0];
}

extern "C" void kernel_launch(void* const* d_in, const int* in_sizes, int n_in,
                              void* d_out, int out_size, void* d_ws, size_t ws_size,
                              hipStream_t stream) {
    const float* stmts    = (const float*)d_in[0];
    const float* eres     = (const float*)d_in[1];
    const float* attender = (const float*)d_in[2];
    const float* Wc_s     = (const float*)d_in[3];
    const float* bc_s     = (const float*)d_in[4];
    const float* ws_s     = (const float*)d_in[5];
    /* d_in[6] = bs_s : softmax-invariant, unused */
    const float* Wc_e     = (const float*)d_in[7];
    const float* bc_e     = (const float*)d_in[8];
    const float* ws_e     = (const float*)d_in[9];
    /* d_in[10] = bs_e : unused */
    const float* W_lin    = (const float*)d_in[11];
    const float* b_lin    = (const float*)d_in[12];
    const float* W_coh    = (const float*)d_in[13];
    const float* b_coh    = (const float*)d_in[14];
    float* out = (float*)d_out;

    float* ws   = (float*)d_ws;
    float* A_s  = ws;               // NS*H
    float* B_s  = A_s + NS * H;     // M*H
    float* A_e  = B_s + M * H;      // NE*H
    float* B_e  = A_e + NE * H;     // M*H
    float* S_s  = B_e + M * H;      // NS*M
    float* S_e  = S_s + NS * M;     // NE*M
    float* mx_s = S_e + NE * M;     // M
    float* sm_s = mx_s + M;
    float* mx_e = sm_s + M;
    float* sm_e = mx_e + M;
    float* c_s  = sm_e + M;         // M*H
    float* c_e  = c_s + M * H;      // M*H

    k_proj<<<NS, H, 0, stream>>>(stmts,    Wc_s, bc_s,    A_s, 0);
    k_proj<<<M,  H, 0, stream>>>(attender, Wc_s, nullptr, B_s, H);
    k_proj<<<NE, H, 0, stream>>>(eres,     Wc_e, bc_e,    A_e, 0);
    k_proj<<<M,  H, 0, stream>>>(attender, Wc_e, nullptr, B_e, H);

    k_score<<<dim3(M / 32, NS / 32), 256, 0, stream>>>(A_s, B_s, ws_s, S_s);
    k_score<<<dim3(M / 32, NE / 32), 256, 0, stream>>>(A_e, B_e, ws_e, S_e);

    k_stats<<<M / 256, 256, 0, stream>>>(S_s, NS, mx_s, sm_s);
    k_stats<<<M / 256, 256, 0, stream>>>(S_e, NE, mx_e, sm_e);

    k_ctx<<<M / TMD, 256, 0, stream>>>(S_s, stmts, mx_s, sm_s, c_s, NS);
    k_ctx<<<M / TMD, 256, 0, stream>>>(S_e, eres,  mx_e, sm_e, c_e, NE);

    k_final<<<M, H, 0, stream>>>(attender, c_s, c_e, W_lin, b_lin, W_coh, b_coh, out);
}

// Round 2
// 174.786 us; speedup vs baseline: 3.2487x; 3.2487x over previous
//
#include <hip/hip_runtime.h>
#include <math.h>

#define H   128
#define NS  1024
#define NE  512
#define M   1024

// tanh(x) = 1 - 2/(exp(2x)+1); exact saturation at both ends.
__device__ __forceinline__ float fast_tanh(float x) {
    float e = __expf(2.0f * x);                 // +inf for large x -> rcp = 0 -> 1
    float r = __builtin_amdgcn_rcpf(1.0f + e);  // ~1 ulp approx rcp
    return 1.0f - 2.0f * r;
}

// out[r,h] = bias[h] + sum_k X[r,k] * W[h, off+k]   (W is [H, 2H] row-major)
__global__ __launch_bounds__(H) void k_proj(const float* __restrict__ X,
                                            const float* __restrict__ W,
                                            const float* __restrict__ bias,
                                            float* __restrict__ out, int off) {
    __shared__ float xr[H];
    int r = blockIdx.x;
    int h = threadIdx.x;
    xr[h] = X[r * H + h];
    __syncthreads();
    const float* wrow = W + h * (2 * H) + off;
    float acc = bias ? bias[h] : 0.0f;
    #pragma unroll 8
    for (int k = 0; k < H; ++k) acc += xr[k] * wrow[k];
    out[r * H + h] = acc;
}

// St[m,n] = sum_h ws[h] * tanh(A[n,h] + B[m,h]);  32(n) x 32(m) tile per block.
// TRANSPOSED output layout [M][N] so softmax stats + ctx reads are coalesced.
__global__ __launch_bounds__(256) void k_score(const float* __restrict__ A,
                                               const float* __restrict__ B,
                                               const float* __restrict__ wsv,
                                               float* __restrict__ St, int N) {
    __shared__ float As[32][H + 1];
    __shared__ float Bs[32][H + 1];
    __shared__ float wls[H];
    int n0 = blockIdx.x * 32;
    int m0 = blockIdx.y * 32;
    int tid = threadIdx.x;
    for (int i = tid; i < 32 * H; i += 256) {
        int rr = i >> 7, cc = i & (H - 1);
        As[rr][cc] = A[(n0 + rr) * H + cc];
        Bs[rr][cc] = B[(m0 + rr) * H + cc];
    }
    if (tid < H) wls[tid] = wsv[tid];
    __syncthreads();

    int tn  = tid & 31;   // n within tile (coalesced store dim)
    int tm4 = tid >> 5;   // 0..7 ; handles m = tm4 + 8*j
    float acc[4] = {0.f, 0.f, 0.f, 0.f};
    #pragma unroll 4
    for (int h = 0; h < H; ++h) {
        float a = As[tn][h];       // stride 129 across lanes: conflict-free
        float w = wls[h];
        #pragma unroll
        for (int j = 0; j < 4; ++j)
            acc[j] += w * fast_tanh(a + Bs[tm4 + 8 * j][h]);  // broadcast
    }
    #pragma unroll
    for (int j = 0; j < 4; ++j)
        St[(size_t)(m0 + tm4 + 8 * j) * N + n0 + tn] = acc[j];
}

// Per-m max and sum(exp(s-max)) over row St[m][0..N); one block per m.
__global__ __launch_bounds__(256) void k_stats(const float* __restrict__ St, int N,
                                               float* __restrict__ mx,
                                               float* __restrict__ sm) {
    int m = blockIdx.x;
    int t = threadIdx.x;
    const float* row = St + (size_t)m * N;
    float vals[4];
    float vmax = -1e30f;
    #pragma unroll
    for (int i = 0; i < 4; ++i) {
        if (i * 256 < N) { vals[i] = row[t + 256 * i]; vmax = fmaxf(vmax, vals[i]); }
        else vals[i] = -1e30f;
    }
    #pragma unroll
    for (int off = 32; off > 0; off >>= 1)
        vmax = fmaxf(vmax, __shfl_xor(vmax, off, 64));
    __shared__ float smx[4], ssm[4];
    int w = t >> 6;
    if ((t & 63) == 0) smx[w] = vmax;
    __syncthreads();
    vmax = fmaxf(fmaxf(smx[0], smx[1]), fmaxf(smx[2], smx[3]));
    float s = 0.f;
    #pragma unroll
    for (int i = 0; i < 4; ++i)
        if (i * 256 < N) s += __expf(vals[i] - vmax);
    #pragma unroll
    for (int off = 32; off > 0; off >>= 1) s += __shfl_xor(s, off, 64);
    if ((t & 63) == 0) ssm[w] = s;
    __syncthreads();
    if (t == 0) { mx[m] = vmax; sm[m] = ssm[0] + ssm[1] + ssm[2] + ssm[3]; }
}

// ctx[m,h] = (1/Z_m) * sum_n exp(St[m,n]-mx_m) * X[n,h];  8 m's per block,
// 256 threads = 2 groups of 128 (h), each group handles half the n-chunk.
#define TMD 8
__global__ __launch_bounds__(256) void k_ctx(const float* __restrict__ St,
                                             const float* __restrict__ X,
                                             const float* __restrict__ mx,
                                             const float* __restrict__ sm,
                                             float* __restrict__ ctx, int N) {
    __shared__ float w[256][TMD + 1];
    __shared__ float part[H][TMD];
    int m0 = blockIdx.x * TMD;
    int tid = threadIdx.x;
    int h = tid & (H - 1);
    int g = tid >> 7;  // 0 or 1
    float cm[TMD], cz[TMD];
    #pragma unroll
    for (int j = 0; j < TMD; ++j) {
        cm[j] = mx[m0 + j];
        cz[j] = __builtin_amdgcn_rcpf(sm[m0 + j]);
    }
    float acc[TMD];
    #pragma unroll
    for (int j = 0; j < TMD; ++j) acc[j] = 0.f;

    for (int nc = 0; nc < N; nc += 256) {
        #pragma unroll
        for (int j = 0; j < TMD; ++j)
            w[tid][j] = __expf(St[(size_t)(m0 + j) * N + nc + tid] - cm[j]);
        __syncthreads();
        int base = g * 128;
        #pragma unroll 8
        for (int nn = 0; nn < 128; ++nn) {
            float x = X[(nc + base + nn) * H + h];
            #pragma unroll
            for (int j = 0; j < TMD; ++j) acc[j] += w[base + nn][j] * x;
        }
        __syncthreads();
    }
    if (g == 1) {
        #pragma unroll
        for (int j = 0; j < TMD; ++j) part[h][j] = acc[j];
    }
    __syncthreads();
    if (g == 0) {
        #pragma unroll
        for (int j = 0; j < TMD; ++j)
            ctx[(m0 + j) * H + h] = (acc[j] + part[h][j]) * cz[j];
    }
}

// coherence[m] = b_coh + sum_a W_coh[a] * tanh(b_lin[a] + feats[m] . W_lin[a,:])
__global__ __launch_bounds__(H) void k_final(const float* __restrict__ attender,
                                             const float* __restrict__ ctx_s,
                                             const float* __restrict__ ctx_e,
                                             const float* __restrict__ W_lin,
                                             const float* __restrict__ b_lin,
                                             const float* __restrict__ W_coh,
                                             const float* __restrict__ b_coh,
                                             float* __restrict__ out) {
    __shared__ float f[3 * H];
    __shared__ float red[2];
    int m = blockIdx.x;
    int t = threadIdx.x;
    f[t]         = attender[m * H + t];
    f[H + t]     = ctx_s[m * H + t];
    f[2 * H + t] = ctx_e[m * H + t];
    __syncthreads();
    const float* wr = W_lin + t * (3 * H);
    float acc = b_lin[t];
    #pragma unroll 8
    for (int k = 0; k < 3 * H; ++k) acc += f[k] * wr[k];
    float v = fast_tanh(acc) * W_coh[t];
    #pragma unroll
    for (int off = 32; off > 0; off >>= 1) v += __shfl_down(v, off, 64);
    if ((t & 63) == 0) red[t >> 6] = v;
    __syncthreads();
    if (t == 0) out[m] = red[0] + red[1] + b_coh[0];
}

extern "C" void kernel_launch(void* const* d_in, const int* in_sizes, int n_in,
                              void* d_out, int out_size, void* d_ws, size_t ws_size,
                              hipStream_t stream) {
    const float* stmts    = (const float*)d_in[0];
    const float* eres     = (const float*)d_in[1];
    const float* attender = (const float*)d_in[2];
    const float* Wc_s     = (const float*)d_in[3];
    const float* bc_s     = (const float*)d_in[4];
    const float* ws_s     = (const float*)d_in[5];
    /* d_in[6] = bs_s : softmax-invariant, unused */
    const float* Wc_e     = (const float*)d_in[7];
    const float* bc_e     = (const float*)d_in[8];
    const float* ws_e     = (const float*)d_in[9];
    /* d_in[10] = bs_e : unused */
    const float* W_lin    = (const float*)d_in[11];
    const float* b_lin    = (const float*)d_in[12];
    const float* W_coh    = (const float*)d_in[13];
    const float* b_coh    = (const float*)d_in[14];
    float* out = (float*)d_out;

    float* ws   = (float*)d_ws;
    float* A_s  = ws;               // NS*H
    float* B_s  = A_s + NS * H;     // M*H
    float* A_e  = B_s + M * H;      // NE*H
    float* B_e  = A_e + NE * H;     // M*H
    float* St_s = B_e + M * H;      // M*NS   (transposed scores)
    float* St_e = St_s + (size_t)M * NS;  // M*NE
    float* mx_s = St_e + (size_t)M * NE;  // M
    float* sm_s = mx_s + M;
    float* mx_e = sm_s + M;
    float* sm_e = mx_e + M;
    float* c_s  = sm_e + M;         // M*H
    float* c_e  = c_s + M * H;      // M*H

    k_proj<<<NS, H, 0, stream>>>(stmts,    Wc_s, bc_s,    A_s, 0);
    k_proj<<<M,  H, 0, stream>>>(attender, Wc_s, nullptr, B_s, H);
    k_proj<<<NE, H, 0, stream>>>(eres,     Wc_e, bc_e,    A_e, 0);
    k_proj<<<M,  H, 0, stream>>>(attender, Wc_e, nullptr, B_e, H);

    k_score<<<dim3(NS / 32, M / 32), 256, 0, stream>>>(A_s, B_s, ws_s, St_s, NS);
    k_score<<<dim3(NE / 32, M / 32), 256, 0, stream>>>(A_e, B_e, ws_e, St_e, NE);

    k_stats<<<M, 256, 0, stream>>>(St_s, NS, mx_s, sm_s);
    k_stats<<<M, 256, 0, stream>>>(St_e, NE, mx_e, sm_e);

    k_ctx<<<M / TMD, 256, 0, stream>>>(St_s, stmts, mx_s, sm_s, c_s, NS);
    k_ctx<<<M / TMD, 256, 0, stream>>>(St_e, eres,  mx_e, sm_e, c_e, NE);

    k_final<<<M, H, 0, stream>>>(attender, c_s, c_e, W_lin, b_lin, W_coh, b_coh, out);
}

// Round 3
// 103.681 us; speedup vs baseline: 5.4767x; 1.6858x over previous
//
#include <hip/hip_runtime.h>
#include <math.h>

#define H   128
#define NS  1024
#define NE  512
#define M   1024
#define K2  2.8853900817779268f   // 2*log2(e): tanh(x) = 1 - 2/(1+exp2(K2*x))

__device__ __forceinline__ float exp2_fast(float x) {
#if __has_builtin(__builtin_amdgcn_exp2f)
    return __builtin_amdgcn_exp2f(x);
#else
    return __expf(x * 0.6931471805599453f);
#endif
}

__device__ __forceinline__ float fast_tanh(float x) {   // unscaled input
    float e = __expf(2.0f * x);
    float r = __builtin_amdgcn_rcpf(1.0f + e);
    return 1.0f - 2.0f * r;
}

// ---- transpose (+scale) the weight matrices ------------------------------
// WT_s1[k][h] = K2*Wc_s[h][k]      WT_s2[k][h] = K2*Wc_s[h][128+k]
// WT_e1/e2 likewise from Wc_e      WT_lin[k][a] = W_lin[a][k]  (384x128)
__global__ __launch_bounds__(256) void k_tr(const float* __restrict__ Wc_s,
                                            const float* __restrict__ Wc_e,
                                            const float* __restrict__ W_lin,
                                            float* __restrict__ WT_s1, float* __restrict__ WT_s2,
                                            float* __restrict__ WT_e1, float* __restrict__ WT_e2,
                                            float* __restrict__ WT_lin) {
    int idx = blockIdx.x * 256 + threadIdx.x;
    if (idx < 65536) {
        int t = idx >> 14, r = idx & 16383, k = r >> 7, hh = r & 127;
        const float* src = (t < 2) ? Wc_s : Wc_e;
        int off = (t & 1) * H;
        float v = K2 * src[hh * 256 + off + k];
        float* dst = (t == 0) ? WT_s1 : (t == 1) ? WT_s2 : (t == 2) ? WT_e1 : WT_e2;
        dst[r] = v;
    } else {
        int j2 = idx - 65536;             // [0, 49152)
        int k = j2 >> 7, a = j2 & 127;
        WT_lin[j2] = W_lin[a * 384 + k];
    }
}

// ---- all four projections, pre-scaled by K2 ------------------------------
__global__ __launch_bounds__(128) void k_proj(const float* __restrict__ stmts,
                                              const float* __restrict__ eres,
                                              const float* __restrict__ attender,
                                              const float* __restrict__ WT_s1,
                                              const float* __restrict__ WT_s2,
                                              const float* __restrict__ WT_e1,
                                              const float* __restrict__ WT_e2,
                                              const float* __restrict__ bc_s,
                                              const float* __restrict__ bc_e,
                                              float* __restrict__ A_s, float* __restrict__ B_s,
                                              float* __restrict__ A_e, float* __restrict__ B_e) {
    int b = blockIdx.x;
    const float *X, *WT, *bias; float* O; int r0;
    if (b < 256)      { X = stmts;    WT = WT_s1; bias = bc_s;    O = A_s; r0 = b * 4; }
    else if (b < 512) { X = attender; WT = WT_s2; bias = nullptr; O = B_s; r0 = (b - 256) * 4; }
    else if (b < 640) { X = eres;     WT = WT_e1; bias = bc_e;    O = A_e; r0 = (b - 512) * 4; }
    else              { X = attender; WT = WT_e2; bias = nullptr; O = B_e; r0 = (b - 640) * 4; }
    __shared__ float xr[4][H];
    int t = threadIdx.x;
    #pragma unroll
    for (int r = 0; r < 4; ++r) xr[r][t] = X[(r0 + r) * H + t];
    __syncthreads();
    float b0 = bias ? K2 * bias[t] : 0.0f;
    float acc[4] = {b0, b0, b0, b0};
    #pragma unroll 8
    for (int k = 0; k < H; ++k) {
        float wv = WT[k * H + t];
        #pragma unroll
        for (int r = 0; r < 4; ++r) acc[r] += xr[r][k] * wv;
    }
    #pragma unroll
    for (int r = 0; r < 4; ++r) O[(r0 + r) * H + t] = acc[r];
}

// ---- scores (both tensors in one launch) ---------------------------------
// St[m][n] = Wtot - 2 * sum_h ws[h] * rcp(1 + exp2(A'[n,h] + B'[m,h]))
__global__ __launch_bounds__(256) void k_score(const float* __restrict__ A_s,
                                               const float* __restrict__ B_s,
                                               const float* __restrict__ ws_s,
                                               const float* __restrict__ A_e,
                                               const float* __restrict__ B_e,
                                               const float* __restrict__ ws_e,
                                               float* __restrict__ St_s,
                                               float* __restrict__ St_e) {
    __shared__ float As[32][H];   // XOR-swizzled: [r][c ^ (r&31)]
    __shared__ float Bs[32][H];
    int bx = blockIdx.x;
    const float *A, *B, *wsv; float* St; int N, n0;
    if (bx < 32) { A = A_s; B = B_s; wsv = ws_s; St = St_s; N = NS; n0 = bx * 32; }
    else         { A = A_e; B = B_e; wsv = ws_e; St = St_e; N = NE; n0 = (bx - 32) * 32; }
    int m0 = blockIdx.y * 32;
    int tid = threadIdx.x;
    for (int i = tid; i < 32 * H; i += 256) {
        int rr = i >> 7, cc = i & 127;
        int sc = cc ^ (rr & 31);
        As[rr][sc] = A[(n0 + rr) * H + cc];
        Bs[rr][sc] = B[(m0 + rr) * H + cc];
    }
    __syncthreads();

    int tn  = tid & 31;
    int tm4 = tid >> 5;          // 0..7
    float acc[4] = {0.f, 0.f, 0.f, 0.f};
    float wtot = 0.f;
    #pragma unroll 4
    for (int hh = 0; hh < H; ++hh) {
        float w = wsv[hh];                       // uniform -> s_load
        wtot += w;
        float a = As[tn][hh ^ tn];
        #pragma unroll
        for (int j = 0; j < 4; ++j) {
            int tm = tm4 + 8 * j;
            float u = a + Bs[tm][hh ^ tm];
            float r = __builtin_amdgcn_rcpf(1.0f + exp2_fast(u));
            acc[j] = fmaf(w, r, acc[j]);
        }
    }
    #pragma unroll
    for (int j = 0; j < 4; ++j)
        St[(size_t)(m0 + tm4 + 8 * j) * N + n0 + tn] = fmaf(-2.f, acc[j], wtot);
}

// ---- fused softmax-stats + context + final MLP ---------------------------
#define TMD 4
__device__ __forceinline__ void reduce4(float v[TMD], bool domax, float (*scr)[TMD]) {
    #pragma unroll
    for (int off = 32; off > 0; off >>= 1) {
        #pragma unroll
        for (int j = 0; j < TMD; ++j) {
            float o = __shfl_xor(v[j], off, 64);
            v[j] = domax ? fmaxf(v[j], o) : (v[j] + o);
        }
    }
    int wv = threadIdx.x >> 6;     // 0..15
    if ((threadIdx.x & 63) == 0) {
        #pragma unroll
        for (int j = 0; j < TMD; ++j) scr[wv][j] = v[j];
    }
    __syncthreads();
    #pragma unroll
    for (int j = 0; j < TMD; ++j) {
        float r = scr[0][j];
        #pragma unroll
        for (int i = 1; i < 16; ++i) r = domax ? fmaxf(r, scr[i][j]) : (r + scr[i][j]);
        v[j] = r;
    }
    __syncthreads();
}

__global__ __launch_bounds__(1024) void k_attend(const float* __restrict__ St_s,
                                                 const float* __restrict__ St_e,
                                                 const float* __restrict__ stmts,
                                                 const float* __restrict__ eres,
                                                 const float* __restrict__ attender,
                                                 const float* __restrict__ WT_lin,
                                                 const float* __restrict__ b_lin,
                                                 const float* __restrict__ W_coh,
                                                 const float* __restrict__ b_coh,
                                                 float* __restrict__ out) {
    __shared__ float wls[1024][TMD + 1];   // +1 pad: conflict-free writes
    __shared__ float part[8][TMD][H];
    __shared__ float feats[TMD][3 * H];
    __shared__ float scr[16][TMD];
    __shared__ float redv[512];
    __shared__ float red8[8];
    int m0  = blockIdx.x * TMD;
    int tid = threadIdx.x;
    int h   = tid & (H - 1);
    int g   = tid >> 7;    // 0..7

    // feats[:, 0:H] = attender rows
    if (tid < TMD * H) feats[tid >> 7][tid & (H - 1)] = attender[(m0 + (tid >> 7)) * H + (tid & (H - 1))];

    // ---- stats: each thread holds one score per row ----
    float vs[TMD], ve[TMD];
    #pragma unroll
    for (int j = 0; j < TMD; ++j) vs[j] = St_s[(size_t)(m0 + j) * NS + tid];
    #pragma unroll
    for (int j = 0; j < TMD; ++j) ve[j] = (tid < NE) ? St_e[(size_t)(m0 + j) * NE + tid] : -1e30f;

    float mxs[TMD], sm_s[TMD], rz_s[TMD], w_s[TMD];
    #pragma unroll
    for (int j = 0; j < TMD; ++j) mxs[j] = vs[j];
    reduce4(mxs, true, scr);
    #pragma unroll
    for (int j = 0; j < TMD; ++j) { w_s[j] = __expf(vs[j] - mxs[j]); sm_s[j] = w_s[j]; }
    reduce4(sm_s, false, scr);
    #pragma unroll
    for (int j = 0; j < TMD; ++j) rz_s[j] = __builtin_amdgcn_rcpf(sm_s[j]);

    float mxe[TMD], sm_e[TMD], rz_e[TMD], w_e[TMD];
    #pragma unroll
    for (int j = 0; j < TMD; ++j) mxe[j] = ve[j];
    reduce4(mxe, true, scr);
    #pragma unroll
    for (int j = 0; j < TMD; ++j) { w_e[j] = __expf(ve[j] - mxe[j]); sm_e[j] = w_e[j]; }
    reduce4(sm_e, false, scr);
    #pragma unroll
    for (int j = 0; j < TMD; ++j) rz_e[j] = __builtin_amdgcn_rcpf(sm_e[j]);

    // ---- ctx_s: 8 n-groups of 128 ----
    #pragma unroll
    for (int j = 0; j < TMD; ++j) wls[tid][j] = w_s[j];
    __syncthreads();
    {
        float acc[TMD] = {0.f, 0.f, 0.f, 0.f};
        const float* Xb = stmts + (size_t)(g * 128) * H + h;
        #pragma unroll 8
        for (int nn = 0; nn < 128; ++nn) {
            float x = Xb[(size_t)nn * H];
            int n = g * 128 + nn;
            #pragma unroll
            for (int j = 0; j < TMD; ++j) acc[j] += wls[n][j] * x;
        }
        #pragma unroll
        for (int j = 0; j < TMD; ++j) part[g][j][h] = acc[j];
    }
    __syncthreads();
    if (tid < 512) {
        int j = tid >> 7, hh = tid & 127;
        float s = 0.f;
        #pragma unroll
        for (int gg = 0; gg < 8; ++gg) s += part[gg][j][hh];
        feats[j][H + hh] = s * rz_s[j];
    }
    __syncthreads();

    // ---- ctx_e: 8 n-groups of 64 ----
    #pragma unroll
    for (int j = 0; j < TMD; ++j) wls[tid][j] = w_e[j];
    __syncthreads();
    {
        float acc[TMD] = {0.f, 0.f, 0.f, 0.f};
        const float* Xb = eres + (size_t)(g * 64) * H + h;
        #pragma unroll 8
        for (int nn = 0; nn < 64; ++nn) {
            float x = Xb[(size_t)nn * H];
            int n = g * 64 + nn;
            #pragma unroll
            for (int j = 0; j < TMD; ++j) acc[j] += wls[n][j] * x;
        }
        #pragma unroll
        for (int j = 0; j < TMD; ++j) part[g][j][h] = acc[j];
    }
    __syncthreads();
    if (tid < 512) {
        int j = tid >> 7, hh = tid & 127;
        float s = 0.f;
        #pragma unroll
        for (int gg = 0; gg < 8; ++gg) s += part[gg][j][hh];
        feats[j][2 * H + hh] = s * rz_e[j];
    }
    __syncthreads();

    // ---- final: att_vec = tanh(feats @ W_lin^T + b_lin); out = att_vec @ W_coh^T + b_coh
    {
        int a    = tid & 127;
        int jm   = (tid >> 7) & 3;
        int half = tid >> 9;               // 0 or 1: k-range split
        float acc = half ? 0.f : b_lin[a];
        int k0 = half * 192;
        #pragma unroll 8
        for (int k = k0; k < k0 + 192; ++k)
            acc += feats[jm][k] * WT_lin[k * H + a];
        if (half) redv[tid & 511] = acc;
        __syncthreads();
        if (!half) {
            acc += redv[tid];
            float v = fast_tanh(acc) * W_coh[a];
            #pragma unroll
            for (int off = 32; off > 0; off >>= 1) v += __shfl_down(v, off, 64);
            if ((tid & 63) == 0) red8[tid >> 6] = v;   // waves 0..7
        }
        __syncthreads();
        if (tid < TMD) out[m0 + tid] = red8[2 * tid] + red8[2 * tid + 1] + b_coh[0];
    }
}

extern "C" void kernel_launch(void* const* d_in, const int* in_sizes, int n_in,
                              void* d_out, int out_size, void* d_ws, size_t ws_size,
                              hipStream_t stream) {
    const float* stmts    = (const float*)d_in[0];
    const float* eres     = (const float*)d_in[1];
    const float* attender = (const float*)d_in[2];
    const float* Wc_s     = (const float*)d_in[3];
    const float* bc_s     = (const float*)d_in[4];
    const float* ws_s     = (const float*)d_in[5];
    /* d_in[6] = bs_s : softmax-invariant */
    const float* Wc_e     = (const float*)d_in[7];
    const float* bc_e     = (const float*)d_in[8];
    const float* ws_e     = (const float*)d_in[9];
    /* d_in[10] = bs_e */
    const float* W_lin    = (const float*)d_in[11];
    const float* b_lin    = (const float*)d_in[12];
    const float* W_coh    = (const float*)d_in[13];
    const float* b_coh    = (const float*)d_in[14];
    float* out = (float*)d_out;

    float* ws    = (float*)d_ws;
    float* WT_s1 = ws;                        // 128*128
    float* WT_s2 = WT_s1 + H * H;
    float* WT_e1 = WT_s2 + H * H;
    float* WT_e2 = WT_e1 + H * H;
    float* WT_li = WT_e2 + H * H;             // 384*128
    float* A_s   = WT_li + 3 * H * H;         // NS*H
    float* B_s   = A_s + NS * H;              // M*H
    float* A_e   = B_s + M * H;               // NE*H
    float* B_e   = A_e + NE * H;              // M*H
    float* St_s  = B_e + M * H;               // M*NS
    float* St_e  = St_s + (size_t)M * NS;     // M*NE

    k_tr<<<448, 256, 0, stream>>>(Wc_s, Wc_e, W_lin, WT_s1, WT_s2, WT_e1, WT_e2, WT_li);
    k_proj<<<896, 128, 0, stream>>>(stmts, eres, attender, WT_s1, WT_s2, WT_e1, WT_e2,
                                    bc_s, bc_e, A_s, B_s, A_e, B_e);
    k_score<<<dim3(48, 32), 256, 0, stream>>>(A_s, B_s, ws_s, A_e, B_e, ws_e, St_s, St_e);
    k_attend<<<M / TMD, 1024, 0, stream>>>(St_s, St_e, stmts, eres, attender, WT_li,
                                           b_lin, W_coh, b_coh, out);
}

// Round 4
// 87.662 us; speedup vs baseline: 6.4776x; 1.1827x over previous
//
#include <hip/hip_runtime.h>
#include <math.h>

#define H   128
#define NS  1024
#define NE  512
#define M   1024
#define K2  2.8853900817779268f   // 2*log2(e): tanh(x) = 1 - 2/(1+exp2(K2*x))

__device__ __forceinline__ float exp2_fast(float x) {
#if __has_builtin(__builtin_amdgcn_exp2f)
    return __builtin_amdgcn_exp2f(x);
#else
    return __expf(x * 0.6931471805599453f);
#endif
}

__device__ __forceinline__ float fast_tanh(float x) {   // unscaled input
    float e = __expf(2.0f * x);
    float r = __builtin_amdgcn_rcpf(1.0f + e);
    return 1.0f - 2.0f * r;
}

// ---- transpose (+scale) the weight matrices ------------------------------
__global__ __launch_bounds__(256) void k_tr(const float* __restrict__ Wc_s,
                                            const float* __restrict__ Wc_e,
                                            const float* __restrict__ W_lin,
                                            float* __restrict__ WT_s1, float* __restrict__ WT_s2,
                                            float* __restrict__ WT_e1, float* __restrict__ WT_e2,
                                            float* __restrict__ WT_lin) {
    int idx = blockIdx.x * 256 + threadIdx.x;
    if (idx < 65536) {
        int t = idx >> 14, r = idx & 16383, k = r >> 7, hh = r & 127;
        const float* src = (t < 2) ? Wc_s : Wc_e;
        int off = (t & 1) * H;
        float v = K2 * src[hh * 256 + off + k];
        float* dst = (t == 0) ? WT_s1 : (t == 1) ? WT_s2 : (t == 2) ? WT_e1 : WT_e2;
        dst[r] = v;
    } else {
        int j2 = idx - 65536;             // [0, 49152)
        int k = j2 >> 7, a = j2 & 127;
        WT_lin[j2] = W_lin[a * 384 + k];
    }
}

// ---- all four projections, pre-scaled by K2 ------------------------------
__global__ __launch_bounds__(128) void k_proj(const float* __restrict__ stmts,
                                              const float* __restrict__ eres,
                                              const float* __restrict__ attender,
                                              const float* __restrict__ WT_s1,
                                              const float* __restrict__ WT_s2,
                                              const float* __restrict__ WT_e1,
                                              const float* __restrict__ WT_e2,
                                              const float* __restrict__ bc_s,
                                              const float* __restrict__ bc_e,
                                              float* __restrict__ A_s, float* __restrict__ B_s,
                                              float* __restrict__ A_e, float* __restrict__ B_e) {
    int b = blockIdx.x;
    const float *X, *WT, *bias; float* O; int r0;
    if (b < 256)      { X = stmts;    WT = WT_s1; bias = bc_s;    O = A_s; r0 = b * 4; }
    else if (b < 512) { X = attender; WT = WT_s2; bias = nullptr; O = B_s; r0 = (b - 256) * 4; }
    else if (b < 640) { X = eres;     WT = WT_e1; bias = bc_e;    O = A_e; r0 = (b - 512) * 4; }
    else              { X = attender; WT = WT_e2; bias = nullptr; O = B_e; r0 = (b - 640) * 4; }
    __shared__ float xr[4][H];
    int t = threadIdx.x;
    #pragma unroll
    for (int r = 0; r < 4; ++r) xr[r][t] = X[(r0 + r) * H + t];
    __syncthreads();
    float b0 = bias ? K2 * bias[t] : 0.0f;
    float acc[4] = {b0, b0, b0, b0};
    #pragma unroll 8
    for (int k = 0; k < H; ++k) {
        float wv = WT[k * H + t];
        #pragma unroll
        for (int r = 0; r < 4; ++r) acc[r] += xr[r][k] * wv;
    }
    #pragma unroll
    for (int r = 0; r < 4; ++r) O[(r0 + r) * H + t] = acc[r];
}

// ---- scores: St[m][n] = -2 * sum_h ws[h] * rcp(1 + exp2(A'[n,h]+B'[m,h]))
// (the wtot shift is softmax-invariant -> dropped)
// A from global via L1 (per-lane row-resident); B tile in 16KB LDS, pulled to
// registers in 8-h chunks so the trans chains are register-only.
__global__ __launch_bounds__(256, 6) void k_score(const float* __restrict__ A_s,
                                                  const float* __restrict__ B_s,
                                                  const float* __restrict__ ws_s,
                                                  const float* __restrict__ A_e,
                                                  const float* __restrict__ B_e,
                                                  const float* __restrict__ ws_e,
                                                  float* __restrict__ St_s,
                                                  float* __restrict__ St_e) {
    __shared__ float Bs[32 * H];   // 16 KB
    int bx = blockIdx.x;
    const float *A, *B, *wsv; float* St; int N, n0;
    if (bx < 32) { A = A_s; B = B_s; wsv = ws_s; St = St_s; N = NS; n0 = bx * 32; }
    else         { A = A_e; B = B_e; wsv = ws_e; St = St_e; N = NE; n0 = (bx - 32) * 32; }
    int m0 = blockIdx.y * 32;
    int tid = threadIdx.x;

    #pragma unroll
    for (int i = 0; i < 4; ++i) {
        int idx = tid + i * 256;   // float4 index over 32*128 floats
        float4 v = *(const float4*)(B + (size_t)m0 * H + idx * 4);
        *(float4*)(Bs + idx * 4) = v;
    }
    __syncthreads();

    int tn  = tid & 31;
    int tm4 = tid >> 5;            // 0..7
    const float* Arow = A + (size_t)(n0 + tn) * H;
    float acc[4] = {0.f, 0.f, 0.f, 0.f};

    #pragma unroll 2
    for (int h0 = 0; h0 < H; h0 += 8) {
        float4 a0 = *(const float4*)(Arow + h0);
        float4 a1 = *(const float4*)(Arow + h0 + 4);
        float af[8] = {a0.x, a0.y, a0.z, a0.w, a1.x, a1.y, a1.z, a1.w};
        float bf[4][8];
        #pragma unroll
        for (int j = 0; j < 4; ++j) {
            const float* brow = Bs + (tm4 + 8 * j) * H + h0;
            float4 b0 = *(const float4*)(brow);       // broadcast b128
            float4 b1 = *(const float4*)(brow + 4);
            bf[j][0] = b0.x; bf[j][1] = b0.y; bf[j][2] = b0.z; bf[j][3] = b0.w;
            bf[j][4] = b1.x; bf[j][5] = b1.y; bf[j][6] = b1.z; bf[j][7] = b1.w;
        }
        #pragma unroll
        for (int k = 0; k < 8; ++k) {
            float w = wsv[h0 + k];                    // uniform -> s_load
            #pragma unroll
            for (int j = 0; j < 4; ++j) {
                float u = af[k] + bf[j][k];
                float r = __builtin_amdgcn_rcpf(1.0f + exp2_fast(u));
                acc[j] = fmaf(w, r, acc[j]);
            }
        }
    }
    #pragma unroll
    for (int j = 0; j < 4; ++j)
        St[(size_t)(m0 + tm4 + 8 * j) * N + n0 + tn] = -2.0f * acc[j];
}

// ---- fused softmax-stats + context + final MLP ---------------------------
#define TMD 4
__device__ __forceinline__ void reduce4(float v[TMD], bool domax, float (*scr)[TMD]) {
    #pragma unroll
    for (int off = 32; off > 0; off >>= 1) {
        #pragma unroll
        for (int j = 0; j < TMD; ++j) {
            float o = __shfl_xor(v[j], off, 64);
            v[j] = domax ? fmaxf(v[j], o) : (v[j] + o);
        }
    }
    int wv = threadIdx.x >> 6;     // 0..15
    if ((threadIdx.x & 63) == 0) {
        #pragma unroll
        for (int j = 0; j < TMD; ++j) scr[wv][j] = v[j];
    }
    __syncthreads();
    #pragma unroll
    for (int j = 0; j < TMD; ++j) {
        float r = scr[0][j];
        #pragma unroll
        for (int i = 1; i < 16; ++i) r = domax ? fmaxf(r, scr[i][j]) : (r + scr[i][j]);
        v[j] = r;
    }
    __syncthreads();
}

__global__ __launch_bounds__(1024) void k_attend(const float* __restrict__ St_s,
                                                 const float* __restrict__ St_e,
                                                 const float* __restrict__ stmts,
                                                 const float* __restrict__ eres,
                                                 const float* __restrict__ attender,
                                                 const float* __restrict__ WT_lin,
                                                 const float* __restrict__ b_lin,
                                                 const float* __restrict__ W_coh,
                                                 const float* __restrict__ b_coh,
                                                 float* __restrict__ out) {
    __shared__ float wls[1024][TMD];       // 16 KB, 16B rows: b128 in/out
    __shared__ float part[8][TMD][H];
    __shared__ float feats[TMD][3 * H];
    __shared__ float scr[16][TMD];
    __shared__ float redv[512];
    __shared__ float red8[8];
    int m0  = blockIdx.x * TMD;
    int tid = threadIdx.x;
    int h   = tid & (H - 1);
    int g   = tid >> 7;    // 0..7

    if (tid < TMD * H) feats[tid >> 7][tid & (H - 1)] = attender[(m0 + (tid >> 7)) * H + (tid & (H - 1))];

    // ---- stats: each thread holds one score per row ----
    float vs[TMD], ve[TMD];
    #pragma unroll
    for (int j = 0; j < TMD; ++j) vs[j] = St_s[(size_t)(m0 + j) * NS + tid];
    #pragma unroll
    for (int j = 0; j < TMD; ++j) ve[j] = (tid < NE) ? St_e[(size_t)(m0 + j) * NE + tid] : -1e30f;

    float mxs[TMD], sm_s[TMD], rz_s[TMD], w_s[TMD];
    #pragma unroll
    for (int j = 0; j < TMD; ++j) mxs[j] = vs[j];
    reduce4(mxs, true, scr);
    #pragma unroll
    for (int j = 0; j < TMD; ++j) { w_s[j] = __expf(vs[j] - mxs[j]); sm_s[j] = w_s[j]; }
    reduce4(sm_s, false, scr);
    #pragma unroll
    for (int j = 0; j < TMD; ++j) rz_s[j] = __builtin_amdgcn_rcpf(sm_s[j]);

    float mxe[TMD], sm_e[TMD], rz_e[TMD], w_e[TMD];
    #pragma unroll
    for (int j = 0; j < TMD; ++j) mxe[j] = ve[j];
    reduce4(mxe, true, scr);
    #pragma unroll
    for (int j = 0; j < TMD; ++j) { w_e[j] = __expf(ve[j] - mxe[j]); sm_e[j] = w_e[j]; }
    reduce4(sm_e, false, scr);
    #pragma unroll
    for (int j = 0; j < TMD; ++j) rz_e[j] = __builtin_amdgcn_rcpf(sm_e[j]);

    // ---- ctx_s ----
    *(float4*)&wls[tid][0] = make_float4(w_s[0], w_s[1], w_s[2], w_s[3]);
    __syncthreads();
    {
        float acc[TMD] = {0.f, 0.f, 0.f, 0.f};
        const float* Xb = stmts + (size_t)(g * 128) * H + h;
        #pragma unroll 8
        for (int nn = 0; nn < 128; ++nn) {
            float x = Xb[(size_t)nn * H];
            float4 w4 = *(const float4*)&wls[g * 128 + nn][0];   // broadcast b128
            acc[0] += w4.x * x; acc[1] += w4.y * x;
            acc[2] += w4.z * x; acc[3] += w4.w * x;
        }
        #pragma unroll
        for (int j = 0; j < TMD; ++j) part[g][j][h] = acc[j];
    }
    __syncthreads();
    if (tid < 512) {
        int j = tid >> 7, hh = tid & 127;
        float s = 0.f;
        #pragma unroll
        for (int gg = 0; gg < 8; ++gg) s += part[gg][j][hh];
        feats[j][H + hh] = s * rz_s[j];
    }
    __syncthreads();

    // ---- ctx_e ----
    *(float4*)&wls[tid][0] = make_float4(w_e[0], w_e[1], w_e[2], w_e[3]);
    __syncthreads();
    {
        float acc[TMD] = {0.f, 0.f, 0.f, 0.f};
        const float* Xb = eres + (size_t)(g * 64) * H + h;
        #pragma unroll 8
        for (int nn = 0; nn < 64; ++nn) {
            float x = Xb[(size_t)nn * H];
            float4 w4 = *(const float4*)&wls[g * 64 + nn][0];
            acc[0] += w4.x * x; acc[1] += w4.y * x;
            acc[2] += w4.z * x; acc[3] += w4.w * x;
        }
        #pragma unroll
        for (int j = 0; j < TMD; ++j) part[g][j][h] = acc[j];
    }
    __syncthreads();
    if (tid < 512) {
        int j = tid >> 7, hh = tid & 127;
        float s = 0.f;
        #pragma unroll
        for (int gg = 0; gg < 8; ++gg) s += part[gg][j][hh];
        feats[j][2 * H + hh] = s * rz_e[j];
    }
    __syncthreads();

    // ---- final MLP + coherence ----
    {
        int a    = tid & 127;
        int jm   = (tid >> 7) & 3;
        int half = tid >> 9;
        float acc = half ? 0.f : b_lin[a];
        int k0 = half * 192;
        #pragma unroll 8
        for (int k = k0; k < k0 + 192; ++k)
            acc += feats[jm][k] * WT_lin[k * H + a];
        if (half) redv[tid & 511] = acc;
        __syncthreads();
        if (!half) {
            acc += redv[tid];
            float v = fast_tanh(acc) * W_coh[a];
            #pragma unroll
            for (int off = 32; off > 0; off >>= 1) v += __shfl_down(v, off, 64);
            if ((tid & 63) == 0) red8[tid >> 6] = v;
        }
        __syncthreads();
        if (tid < TMD) out[m0 + tid] = red8[2 * tid] + red8[2 * tid + 1] + b_coh[0];
    }
}

extern "C" void kernel_launch(void* const* d_in, const int* in_sizes, int n_in,
                              void* d_out, int out_size, void* d_ws, size_t ws_size,
                              hipStream_t stream) {
    const float* stmts    = (const float*)d_in[0];
    const float* eres     = (const float*)d_in[1];
    const float* attender = (const float*)d_in[2];
    const float* Wc_s     = (const float*)d_in[3];
    const float* bc_s     = (const float*)d_in[4];
    const float* ws_s     = (const float*)d_in[5];
    const float* Wc_e     = (const float*)d_in[7];
    const float* bc_e     = (const float*)d_in[8];
    const float* ws_e     = (const float*)d_in[9];
    const float* W_lin    = (const float*)d_in[11];
    const float* b_lin    = (const float*)d_in[12];
    const float* W_coh    = (const float*)d_in[13];
    const float* b_coh    = (const float*)d_in[14];
    float* out = (float*)d_out;

    float* ws    = (float*)d_ws;
    float* WT_s1 = ws;
    float* WT_s2 = WT_s1 + H * H;
    float* WT_e1 = WT_s2 + H * H;
    float* WT_e2 = WT_e1 + H * H;
    float* WT_li = WT_e2 + H * H;             // 384*128
    float* A_s   = WT_li + 3 * H * H;
    float* B_s   = A_s + NS * H;
    float* A_e   = B_s + M * H;
    float* B_e   = A_e + NE * H;
    float* St_s  = B_e + M * H;
    float* St_e  = St_s + (size_t)M * NS;

    k_tr<<<448, 256, 0, stream>>>(Wc_s, Wc_e, W_lin, WT_s1, WT_s2, WT_e1, WT_e2, WT_li);
    k_proj<<<896, 128, 0, stream>>>(stmts, eres, attender, WT_s1, WT_s2, WT_e1, WT_e2,
                                    bc_s, bc_e, A_s, B_s, A_e, B_e);
    k_score<<<dim3(48, 32), 256, 0, stream>>>(A_s, B_s, ws_s, A_e, B_e, ws_e, St_s, St_e);
    k_attend<<<M / TMD, 1024, 0, stream>>>(St_s, St_e, stmts, eres, attender, WT_li,
                                           b_lin, W_coh, b_coh, out);
}